// Round 2
// baseline (6704.055 us; speedup 1.0000x reference)
//
#include <hip/hip_runtime.h>
#include <math.h>

#define B 2048
#define T 48
#define C 35
#define NUM 19
#define H 128
#define R 4              // batch rows per block
#define NBLK (B / R)     // 512 blocks -> 2 blocks/CU
#define NTHR 256
#define K2C 70           // 2*C
#define KG 198           // 2*C + H
#define G4 512           // 4*H
#define NO 665           // NUM*C

// ws layout (floats)
#define WS_MSUM 0                       // [48] msum accumulators (atomicAdd)
#define WS_WGT  64                      // [198][512] gates weights^T (cc|mt|h)
#define WS_GB   (WS_WGT + KG * G4)      // [512] b_ih + b_hh
#define WS_WCT  (WS_GB + G4)            // [70][665] w_comb^T
#define WS_WDHT (WS_WCT + K2C * NO)     // [35][128] w_dh^T
#define WS_WHRT (WS_WDHT + C * H)       // [128][35] w_hr^T
#define WS_FRT  (WS_WHRT + H * C)       // [35][35] fr_w^T (zero diag)

__device__ __forceinline__ float fast_sigmoid(float x) {
    return __builtin_amdgcn_rcpf(1.f + __expf(-x));
}
__device__ __forceinline__ float fast_tanh(float x) {
    return 1.f - 2.f * __builtin_amdgcn_rcpf(1.f + __expf(2.f * x));
}

__global__ __launch_bounds__(256)
void prep_kernel(const float* __restrict__ mask,
                 const float* __restrict__ w_dh,
                 const float* __restrict__ w_hr,
                 const float* __restrict__ w_fr,
                 const float* __restrict__ w_comb,
                 const float* __restrict__ w_ih,
                 const float* __restrict__ w_hh,
                 const float* __restrict__ b_ih,
                 const float* __restrict__ b_hh,
                 float* __restrict__ ws) {
    int blk = blockIdx.x, tid = threadIdx.x;
    if (blk < 192) {
        // msum partial: t = blk>>2, batch slice s = blk&3 (512 rows)
        int t = blk >> 2, s = blk & 3;
        int b0 = s * 512;
        float sum = 0.f;
        for (int i = tid; i < 512 * C; i += 256) {
            int b = i / C, c = i % C;
            sum += mask[((size_t)(b0 + b) * T + t) * C + c];
        }
        __shared__ float red[256];
        red[tid] = sum;
        __syncthreads();
        for (int off = 128; off > 0; off >>= 1) {
            if (tid < off) red[tid] += red[tid + off];
            __syncthreads();
        }
        if (tid == 0) atomicAdd(&ws[WS_MSUM + t], red[0]);
    } else {
        int gt = (blk - 192) * 256 + tid;  // 0..16383
        for (int i = gt; i < KG * G4; i += 16384) {
            int k = i / G4, j = i % G4;
            ws[WS_WGT + i] = (k < K2C) ? w_ih[j * K2C + k] : w_hh[j * H + (k - K2C)];
        }
        for (int j = gt; j < G4; j += 16384) ws[WS_GB + j] = b_ih[j] + b_hh[j];
        for (int i = gt; i < K2C * NO; i += 16384) {
            int f = i / NO, no = i % NO;
            ws[WS_WCT + i] = w_comb[no * K2C + f];
        }
        for (int i = gt; i < C * H; i += 16384) {
            int k = i / H, j = i % H;
            ws[WS_WDHT + i] = w_dh[j * C + k];
        }
        for (int i = gt; i < H * C; i += 16384) {
            int k = i / C, o = i % C;
            ws[WS_WHRT + i] = w_hr[o * H + k];
        }
        for (int i = gt; i < C * C; i += 16384) {
            int k = i / C, o = i % C;
            ws[WS_FRT + i] = (k == o) ? 0.f : w_fr[o * C + k];
        }
    }
}

__global__ __launch_bounds__(NTHR, 4)
void main_kernel(const float* __restrict__ x, const float* __restrict__ mask,
                 const float* __restrict__ delta,
                 const float* __restrict__ b_dh, const float* __restrict__ w_dx,
                 const float* __restrict__ b_dx, const float* __restrict__ b_hr,
                 const float* __restrict__ b_fr, const float* __restrict__ b_comb,
                 const float* __restrict__ ws, float* __restrict__ out) {
    __shared__ float sh[R][H];     // hidden state
    __shared__ float scl[R][H];    // cell state
    __shared__ float sx[R][C];
    __shared__ float sdt[R][C];
    __shared__ float scat[R][K2C]; // [gamma_x | mask]
    __shared__ float sxh[R][C];
    __shared__ float sxc[R][C];
    __shared__ float szh[R][C];
    __shared__ float scc[R][C];
    __shared__ float sbig[R * NUM * C];  // aliased: temp_h (P4-P5) / gates (P6-P7) / reduce

    float (*stemp)[NUM][C] = (float (*)[NUM][C])sbig;
    float (*sg)[G4] = (float (*)[G4])sbig;

    const int tid = threadIdx.x;
    const int b0 = blockIdx.x * R;
    const float* WgT  = ws + WS_WGT;
    const float* gb   = ws + WS_GB;
    const float* WcT  = ws + WS_WCT;
    const float* wdhT = ws + WS_WDHT;
    const float* whrT = ws + WS_WHRT;
    const float* frT  = ws + WS_FRT;
    float* imp = out + 1;
    float* ens = out + 1 + (size_t)B * T * C;

    for (int i = tid; i < R * H; i += NTHR) { ((float*)sh)[i] = 0.f; ((float*)scl)[i] = 0.f; }
    float loss = 0.f;
    __syncthreads();

    for (int t = 0; t < T; ++t) {
        const float inv_msum = 1.0f / (ws[WS_MSUM + t] + 1e-5f);

        // P0: load x, mask, delta; gamma_x
        if (tid < R * C) {
            int r = tid / C, c = tid % C;
            size_t gi = ((size_t)(b0 + r) * T + t) * C + c;
            float xv = x[gi], mv = mask[gi], dv = delta[gi];
            sx[r][c] = xv; sdt[r][c] = dv;
            scat[r][c] = __expf(-fmaxf(dv * w_dx[c * C + c] + b_dx[c], 0.f));
            scat[r][C + c] = mv;
        }
        __syncthreads();

        // P1: gamma_h, decay h
        for (int i = tid; i < R * H; i += NTHR) {
            int r = i / H, j = i % H;
            float d = b_dh[j];
            for (int k = 0; k < C; ++k) d += wdhT[k * H + j] * sdt[r][k];
            sh[r][j] *= __expf(-fmaxf(d, 0.f));
        }
        __syncthreads();

        // P2: x_h = h @ w_hr^T + b_hr; loss1; x_c
        float l_acc = 0.f;
        if (tid < R * C) {
            int r = tid / C, o = tid % C;
            float d = b_hr[o];
            for (int k = 0; k < H; ++k) d += whrT[k * C + o] * sh[r][k];
            float xv = sx[r][o], mv = scat[r][C + o];
            sxh[r][o] = d;
            l_acc += fabsf(xv - d) * mv;
            sxc[r][o] = mv * xv + (1.f - mv) * d;
        }
        __syncthreads();

        // P3: z_h = x_c @ fr_w^T + b_fr; loss2
        if (tid < R * C) {
            int r = tid / C, o = tid % C;
            float d = b_fr[o];
            for (int k = 0; k < C; ++k) d += frT[k * C + o] * sxc[r][k];
            szh[r][o] = d;
            l_acc += fabsf(sx[r][o] - d) * scat[r][C + o];
        }
        __syncthreads();

        // P4: alpha GEMM -> temp_h, quantile loss, ens write
        float ql = 0.f;
        for (int idx = tid; idx < NO; idx += NTHR) {
            int n = idx / C, o = idx % C;
            float q = 0.05f * (float)(n + 1);
            float acc[R];
            float bc = b_comb[idx];
#pragma unroll
            for (int r = 0; r < R; ++r) acc[r] = bc;
            const float* wp = WcT + idx;
            for (int f = 0; f < K2C; ++f) {
                float w = wp[f * NO];
#pragma unroll
                for (int r = 0; r < R; ++r) acc[r] += w * scat[r][f];
            }
#pragma unroll
            for (int r = 0; r < R; ++r) {
                float zh = szh[r][o], xh = sxh[r][o];
                float th = acc[r] * zh + (1.f - acc[r]) * xh;
                stemp[r][n][o] = th;
                float xv = sx[r][o], mv = scat[r][C + o];
                float ind = ((xv <= th) ? 1.f : 0.f) - q;
                ql += fabsf((th - xv) * mv * ind);
                ens[(((size_t)(b0 + r) * NUM + n) * T + t) * C + o] =
                    mv * xv + (1.f - mv) * th;
            }
        }
        l_acc += ql * (1.f / NUM);
        __syncthreads();

        // P5: mean over NUM; loss4; c_c; imp write
        if (tid < R * C) {
            int r = tid / C, o = tid % C;
            float s = 0.f;
#pragma unroll
            for (int n = 0; n < NUM; ++n) s += stemp[r][n][o];
            float tm = s * (1.f / NUM);
            float xv = sx[r][o], mv = scat[r][C + o];
            l_acc += fabsf(xv - tm) * mv;
            float cc = mv * xv + (1.f - mv) * tm;
            scc[r][o] = cc;
            imp[((size_t)(b0 + r) * T + t) * C + o] = cc;
        }
        loss += l_acc * inv_msum;
        __syncthreads();   // also protects sbig reuse (temp -> gates)

        // P6: gates = [c_c|mt] @ w_ih^T + h @ w_hh^T + biases; 2 cols/thread
        {
            const int j0 = 2 * tid;
            float acc0[R], acc1[R];
            float bv0 = gb[j0], bv1 = gb[j0 + 1];
#pragma unroll
            for (int r = 0; r < R; ++r) { acc0[r] = bv0; acc1[r] = bv1; }
            const float* wp = WgT + j0;
            for (int k = 0; k < C; ++k) {
                float2 w = *(const float2*)(wp + k * G4);
#pragma unroll
                for (int r = 0; r < R; ++r) {
                    float s = scc[r][k];
                    acc0[r] += w.x * s; acc1[r] += w.y * s;
                }
            }
            for (int k = C; k < K2C; ++k) {
                float2 w = *(const float2*)(wp + k * G4);
#pragma unroll
                for (int r = 0; r < R; ++r) {
                    float s = scat[r][k];          // mask lives at scat[r][35..69]
                    acc0[r] += w.x * s; acc1[r] += w.y * s;
                }
            }
            for (int k = 0; k < H; ++k) {
                float2 w = *(const float2*)(wp + (K2C + k) * G4);
#pragma unroll
                for (int r = 0; r < R; ++r) {
                    float s = sh[r][k];
                    acc0[r] += w.x * s; acc1[r] += w.y * s;
                }
            }
#pragma unroll
            for (int r = 0; r < R; ++r) { sg[r][j0] = acc0[r]; sg[r][j0 + 1] = acc1[r]; }
        }
        __syncthreads();

        // P7: LSTM cell update
        for (int i = tid; i < R * H; i += NTHR) {
            int r = i / H, jj = i % H;
            float ig = sg[r][jj], fg = sg[r][H + jj];
            float gg = sg[r][2 * H + jj], og = sg[r][3 * H + jj];
            float si = fast_sigmoid(ig);
            float sf = fast_sigmoid(fg);
            float so = fast_sigmoid(og);
            float tg = fast_tanh(gg);
            float cv = sf * scl[r][jj] + si * tg;
            scl[r][jj] = cv;
            sh[r][jj] = so * fast_tanh(cv);
        }
        __syncthreads();
    }

    // final loss reduction (reuse sbig)
    float* red = sbig;
    red[tid] = loss;
    __syncthreads();
    for (int off = NTHR / 2; off > 0; off >>= 1) {
        if (tid < off) red[tid] += red[tid + off];
        __syncthreads();
    }
    if (tid == 0) atomicAdd(out, red[0] * (1.f / (float)T));
}

extern "C" void kernel_launch(void* const* d_in, const int* in_sizes, int n_in,
                              void* d_out, int out_size, void* d_ws, size_t ws_size,
                              hipStream_t stream) {
    const float* x      = (const float*)d_in[0];
    const float* mask   = (const float*)d_in[1];
    const float* delta  = (const float*)d_in[2];
    const float* w_dh   = (const float*)d_in[3];
    const float* b_dh   = (const float*)d_in[4];
    const float* w_dx   = (const float*)d_in[5];
    const float* b_dx   = (const float*)d_in[6];
    const float* w_hr   = (const float*)d_in[7];
    const float* b_hr   = (const float*)d_in[8];
    const float* w_fr   = (const float*)d_in[9];
    const float* b_fr   = (const float*)d_in[10];
    const float* w_comb = (const float*)d_in[11];
    const float* b_comb = (const float*)d_in[12];
    const float* w_ih   = (const float*)d_in[13];
    const float* w_hh   = (const float*)d_in[14];
    const float* b_ih   = (const float*)d_in[15];
    const float* b_hh   = (const float*)d_in[16];
    float* out = (float*)d_out;
    float* ws  = (float*)d_ws;

    // zero msum accumulators + loss cell (re-poisoned to 0xAA before every launch)
    hipMemsetAsync(ws, 0, 64 * sizeof(float), stream);
    hipMemsetAsync(d_out, 0, sizeof(float), stream);
    prep_kernel<<<256, 256, 0, stream>>>(mask, w_dh, w_hr, w_fr, w_comb, w_ih, w_hh,
                                         b_ih, b_hh, ws);
    main_kernel<<<NBLK, NTHR, 0, stream>>>(x, mask, delta, b_dh, w_dx, b_dx, b_hr,
                                           b_fr, b_comb, ws, out);
}

// Round 6
// 4199.939 us; speedup vs baseline: 1.5962x; 1.5962x over previous
//
#include <hip/hip_runtime.h>
#include <math.h>

#define B 2048
#define T 48
#define C 35
#define NUM 19
#define H 128
#define R 8
#define NBLK (B / R)     // 256 blocks
#define NTHR 1024
#define G4 512           // 4*H
#define KGS 232          // gates A LDS row stride (logical 224: h|cc|mt|pad)

// ws layout: fp32 region (float offsets)
#define WS_MSUM 0                   // [48] mask sums (atomicAdd)
#define WS_WDHT 64                  // [35][128] w_dh^T
#define WS_WHRT (WS_WDHT + 4480)    // [128][35] w_hr^T            -> 9024
#define WS_FRT  (WS_WHRT + 4480)    // [35][35] fr_w^T (zero diag) -> 10256 (pad)
#define WS_GB   (WS_FRT + 1232)     // [512] b_ih + b_hh           -> 10768
#define WS_WCTP (WS_GB + 512)       // [70][35][20] w_comb packed  -> 59768
#define WS_F32END (WS_WCTP + 49000) // 59768 floats (239072 B, 16B aligned)
// bf16 region (ushort offsets from wsb)
#define WGB 0                       // [32 nt][7 kt][64 lane][8] gates B-frags
#define WGB_SZ (32 * 7 * 512)       // 114688 ushorts

typedef __attribute__((ext_vector_type(8))) short short8;
typedef __attribute__((ext_vector_type(4))) float f32x4;

__device__ __forceinline__ ushort f2bf(float f) {
    unsigned u = __float_as_uint(f);
    unsigned r = (u + 0x7fff + ((u >> 16) & 1)) >> 16;
    return (ushort)r;
}
__device__ __forceinline__ float rl(float v, int k) {
    return __int_as_float(__builtin_amdgcn_readlane(__float_as_int(v), k));
}
__device__ __forceinline__ float fast_sigmoid(float x) {
    return __builtin_amdgcn_rcpf(1.f + __expf(-x));
}
__device__ __forceinline__ float fast_tanh(float x) {
    return 1.f - 2.f * __builtin_amdgcn_rcpf(1.f + __expf(2.f * x));
}
__device__ __forceinline__ f32x4 mfma16(short8 a, short8 b, f32x4 c) {
    return __builtin_amdgcn_mfma_f32_16x16x32_bf16(a, b, c, 0, 0, 0);
}

__global__ __launch_bounds__(256)
void prep_kernel(const float* __restrict__ mask,
                 const float* __restrict__ w_dh, const float* __restrict__ w_hr,
                 const float* __restrict__ w_fr, const float* __restrict__ w_comb,
                 const float* __restrict__ w_ih, const float* __restrict__ w_hh,
                 const float* __restrict__ b_ih, const float* __restrict__ b_hh,
                 float* __restrict__ ws) {
    int blk = blockIdx.x, tid = threadIdx.x;
    if (blk < 192) {
        int t = blk >> 2, s = blk & 3;
        int b0 = s * 512;
        float sum = 0.f;
        for (int i = tid; i < 512 * C; i += 256) {
            int b = i / C, c = i % C;
            sum += mask[((size_t)(b0 + b) * T + t) * C + c];
        }
        __shared__ float red[256];
        red[tid] = sum;
        __syncthreads();
        for (int off = 128; off > 0; off >>= 1) {
            if (tid < off) red[tid] += red[tid + off];
            __syncthreads();
        }
        if (tid == 0) atomicAdd(&ws[WS_MSUM + t], red[0]);
    } else {
        const int NP = 64 * 256;
        int gt = (blk - 192) * 256 + tid;
        ushort* wsb = (ushort*)(ws + WS_F32END);
        for (int i = gt; i < 4480; i += NP) {            // wdhT[k][j]
            int k = i / 128, j = i % 128;
            ws[WS_WDHT + i] = w_dh[j * C + k];
        }
        for (int i = gt; i < 4480; i += NP) {            // whrT[k][o]
            int k = i / 35, o = i % 35;
            ws[WS_WHRT + i] = w_hr[o * H + k];
        }
        for (int i = gt; i < 1225; i += NP) {            // frT[k][o]
            int k = i / 35, o = i % 35;
            ws[WS_FRT + i] = (k == o) ? 0.f : w_fr[o * C + k];
        }
        for (int i = gt; i < 512; i += NP) ws[WS_GB + i] = b_ih[i] + b_hh[i];
        // w_comb packed fp32: WCTP[f][c][n'] (n' 0..19, 19 = pad 0)
        for (int i = gt; i < 49000; i += NP) {
            int n = i % 20, rest = i / 20;
            int c = rest % 35, f = rest / 35;
            ws[WS_WCTP + i] = (n < NUM) ? w_comb[(n * C + c) * 70 + f] : 0.f;
        }
        // gates B-frags (single bf16): G[n][k], k = [h(128) | cc(35) | mt(35) | 0]
        for (int i = gt; i < WGB_SZ; i += NP) {
            int j = i & 7, lane = (i >> 3) & 63, tile = i >> 9;
            int kt = tile % 7, nt = tile / 7;
            int n = nt * 16 + (lane & 15);
            int k = kt * 32 + ((lane >> 4) << 3) + j;
            float v = (k < 128) ? w_hh[n * H + k]
                    : (k < 198 ? w_ih[n * 70 + (k - 128)] : 0.f);
            wsb[WGB + i] = f2bf(v);
        }
    }
}

__global__ __launch_bounds__(NTHR, 4)
void main_kernel(const float* __restrict__ x, const float* __restrict__ mask,
                 const float* __restrict__ delta,
                 const float* __restrict__ b_dh, const float* __restrict__ w_dx,
                 const float* __restrict__ b_dx, const float* __restrict__ b_hr,
                 const float* __restrict__ b_fr, const float* __restrict__ b_comb,
                 const float* __restrict__ ws, float* __restrict__ out) {
    __shared__ float sh[R][H];        // fp32 hidden
    __shared__ float scl[R][H];       // fp32 cell
    __shared__ float sdt[R][C];       // delta
    __shared__ float sxc[R][C];       // x_c (fp32)
    __shared__ __align__(16) ushort sgin[16][KGS];  // bf16 gates A
    __shared__ float sg[R * G4];      // gates output / final reduce

    const int tid = threadIdx.x;
    const int wv = tid >> 6, lane = tid & 63, quad = lane >> 4, l15 = lane & 15;
    const int b0 = blockIdx.x * R;
    const float* wdhT = ws + WS_WDHT;
    const float* whrT = ws + WS_WHRT;
    const float* frT  = ws + WS_FRT;
    const float* gb   = ws + WS_GB;
    const float* wctp = ws + WS_WCTP;
    const ushort* wsb = (const ushort*)(ws + WS_F32END);
    const short8* wgB = (const short8*)(wsb + WGB);
    float* imp = out + 1;
    float* ens = out + 1 + (size_t)B * T * C;

    for (int i = tid; i < R * H; i += NTHR) { ((float*)sh)[i] = 0.f; ((float*)scl)[i] = 0.f; }
    for (int i = tid; i < 16 * KGS; i += NTHR) ((ushort*)sgin)[i] = 0;
    float loss = 0.f;
    __syncthreads();

    for (int t = 0; t < T; ++t) {
        const float inv_msum = 1.0f / (ws[WS_MSUM + t] + 1e-5f);
        float xv = 0.f, mv = 0.f, vg = 0.f;
        float l_acc = 0.f;

        // ---- P0: waves 0..7, lanes 0..34: load x/mask/delta; gamma_x (register)
        if (tid < 512 && lane < C) {
            size_t gi = ((size_t)(b0 + wv) * T + t) * C + lane;
            xv = x[gi]; mv = mask[gi];
            float dv = delta[gi];
            sdt[wv][lane] = dv;
            vg = __expf(-fmaxf(dv * w_dx[lane * C + lane] + b_dx[lane], 0.f));
            sgin[wv][163 + lane] = f2bf(mv);
        }
        __syncthreads();

        // ---- P1: decay h (all 1024 threads; LDS-broadcast reads of sdt)
        {
            int r = tid >> 7, j = tid & 127;
            float d = b_dh[j];
            for (int k = 0; k < C; ++k)
                d = fmaf(sdt[r][k], wdhT[k * H + j], d);
            float hv = sh[r][j] * __expf(-fmaxf(d, 0.f));
            sh[r][j] = hv;
            sgin[r][j] = f2bf(hv);
        }
        __syncthreads();

        // ---- P2+P3+alpha+epilogue: waves 0..7, lanes 0..34, fp32 throughout
        if (tid < 512 && lane < C) {
            // x_h = h @ w_hr^T + b_hr (LDS-broadcast sh reads)
            float xh = b_hr[lane];
            for (int k = 0; k < H; ++k)
                xh = fmaf(sh[wv][k], whrT[k * C + lane], xh);
            l_acc += fabsf(xv - xh) * mv;
            float xc = fmaf(mv, xv - xh, xh);
            sxc[wv][lane] = xc;   // same-wave LDS write-then-read (in-order)
            // z_h = x_c @ fr_w^T + b_fr
            float zh = b_fr[lane];
            for (int k = 0; k < C; ++k)
                zh = fmaf(sxc[wv][k], frT[k * C + lane], zh);
            l_acc += fabsf(xv - zh) * mv;

            // alpha[n] fp32: cat=[gamma(35)|mask(35)] dot w_comb rows
            float acc[20];
#pragma unroll
            for (int n = 0; n < NUM; ++n) acc[n] = b_comb[n * C + lane];
            acc[19] = 0.f;
            for (int f = 0; f < 70; ++f) {
                float gf = (f < C) ? rl(vg, f) : rl(mv, f - C);
                const float4* wq = (const float4*)(wctp + (f * C + lane) * 20);
#pragma unroll
                for (int q = 0; q < 5; ++q) {
                    float4 w4 = wq[q];
                    acc[4 * q + 0] = fmaf(gf, w4.x, acc[4 * q + 0]);
                    acc[4 * q + 1] = fmaf(gf, w4.y, acc[4 * q + 1]);
                    acc[4 * q + 2] = fmaf(gf, w4.z, acc[4 * q + 2]);
                    acc[4 * q + 3] = fmaf(gf, w4.w, acc[4 * q + 3]);
                }
            }

            // quantile / ensemble epilogue
            float ql = 0.f, sth = 0.f;
            float dzx = zh - xh;
#pragma unroll
            for (int n = 0; n < NUM; ++n) {
                float th = fmaf(acc[n], dzx, xh);
                float ind = ((xv <= th) ? 1.f : 0.f) - 0.05f * (float)(n + 1);
                ql += fabsf((th - xv) * mv * ind);
                sth += th;
                ens[(((size_t)(b0 + wv) * NUM + n) * T + t) * C + lane] =
                    fmaf(mv, xv - th, th);
            }
            l_acc += ql * (1.f / NUM);
            float tm = sth * (1.f / NUM);
            l_acc += fabsf(xv - tm) * mv;
            float cc = fmaf(mv, xv - tm, tm);
            imp[((size_t)(b0 + wv) * T + t) * C + lane] = cc;
            sgin[wv][128 + lane] = f2bf(cc);
        }
        loss += l_acc * inv_msum;
        __syncthreads();

        // ---- P6-MFMA: gates = sgin @ G^T (single bf16; 2 N-tiles/wave)
        {
            f32x4 g0 = {0.f, 0.f, 0.f, 0.f}, g1 = g0;
            int nt0 = wv, nt1 = wv + 16;
#pragma unroll
            for (int kt = 0; kt < 7; ++kt) {
                short8 a = *(const short8*)&sgin[l15][kt * 32 + quad * 8];
                g0 = mfma16(a, wgB[(nt0 * 7 + kt) * 64 + lane], g0);
                g1 = mfma16(a, wgB[(nt1 * 7 + kt) * 64 + lane], g1);
            }
            if (quad < 2) {
#pragma unroll
                for (int reg = 0; reg < 4; ++reg) {
                    int row = quad * 4 + reg;
                    sg[row * G4 + nt0 * 16 + l15] = g0[reg];
                    sg[row * G4 + nt1 * 16 + l15] = g1[reg];
                }
            }
        }
        __syncthreads();

        // ---- P7: LSTM cell update (all 1024 threads)
        {
            int r = tid >> 7, j = tid & 127;
            float ig = sg[r * G4 + j]       + gb[j];
            float fg = sg[r * G4 + 128 + j] + gb[128 + j];
            float gg = sg[r * G4 + 256 + j] + gb[256 + j];
            float og = sg[r * G4 + 384 + j] + gb[384 + j];
            float cv = fast_sigmoid(fg) * scl[r][j] + fast_sigmoid(ig) * fast_tanh(gg);
            scl[r][j] = cv;
            sh[r][j] = fast_sigmoid(og) * fast_tanh(cv);
        }
        __syncthreads();
    }

    // final loss reduction (reuse sg)
    sg[tid] = loss;
    __syncthreads();
    for (int off = NTHR / 2; off > 0; off >>= 1) {
        if (tid < off) sg[tid] += sg[tid + off];
        __syncthreads();
    }
    if (tid == 0) atomicAdd(out, sg[0] * (1.f / (float)T));
}

extern "C" void kernel_launch(void* const* d_in, const int* in_sizes, int n_in,
                              void* d_out, int out_size, void* d_ws, size_t ws_size,
                              hipStream_t stream) {
    const float* x      = (const float*)d_in[0];
    const float* mask   = (const float*)d_in[1];
    const float* delta  = (const float*)d_in[2];
    const float* w_dh   = (const float*)d_in[3];
    const float* b_dh   = (const float*)d_in[4];
    const float* w_dx   = (const float*)d_in[5];
    const float* b_dx   = (const float*)d_in[6];
    const float* w_hr   = (const float*)d_in[7];
    const float* b_hr   = (const float*)d_in[8];
    const float* w_fr   = (const float*)d_in[9];
    const float* b_fr   = (const float*)d_in[10];
    const float* w_comb = (const float*)d_in[11];
    const float* b_comb = (const float*)d_in[12];
    const float* w_ih   = (const float*)d_in[13];
    const float* w_hh   = (const float*)d_in[14];
    const float* b_ih   = (const float*)d_in[15];
    const float* b_hh   = (const float*)d_in[16];
    float* out = (float*)d_out;
    float* ws  = (float*)d_ws;

    hipMemsetAsync(ws, 0, 64 * sizeof(float), stream);   // msum accumulators
    hipMemsetAsync(d_out, 0, sizeof(float), stream);     // loss cell
    prep_kernel<<<256, 256, 0, stream>>>(mask, w_dh, w_hr, w_fr, w_comb, w_ih, w_hh,
                                         b_ih, b_hh, ws);
    main_kernel<<<NBLK, NTHR, 0, stream>>>(x, mask, delta, b_dh, w_dx, b_dx, b_hr,
                                           b_fr, b_comb, ws, out);
}